// Round 1
// baseline (587.320 us; speedup 1.0000x reference)
//
#include <hip/hip_runtime.h>
#include <stdint.h>

// dx/dt = F - B*x - r * rowsum(x * (A@x))  broadcast over DIM
// A: 10000x10000 f32 streamed once (400MB -> ~63.5us HBM floor).
// A@x via bf16 MFMA 16x16x32 (absmax 4.0 vs threshold 20.64 — verified R1).
//
// R5: barrier-free streaming gemm. Timing decomposition: timed iter =
// harness ws-poison fill (~245us, untouchable) + gemm (~240us) + pack/final
// (~15us). R4's per-chunk {issue loads -> MFMA -> pack (vmcnt(0) drain) ->
// __syncthreads} cycle drops in-flight HBM bytes to zero at every barrier
// (20x per block) -> ~50% duty cycle -> 1.7 TB/s effective. Fix: no LDS,
// no barriers. Each wave loads its MFMA A-fragments straight to registers
// (per lane: 32B contiguous; per wave-instr: 16 rows x 128B segments),
// packs bf16 in-reg, 4-deep tile prefetch, 2-deep B prefetch, 5000
// independent waves. Predict gemm -> 75-95us, total -> ~350-370us.

#define N_ROWS 10000
#define DIM 64
#define KTILE 32
#define NKT 320     // K padded to 10240: 320 tiles of 32; B zero-filled past 10000
#define KSPLIT 2    // blockIdx.y K-split; 4 waves/block -> 8 K-segments
#define TPW 40      // tiles per wave = NKT / (KSPLIT*4)
#define PF 4        // A-tile prefetch depth (registers)
#define F_CONST 1.0f
#define B_CONST 0.1f
#define R_CONST 0.01f

#define SACC_OFF_BYTES 1310720  // packed B ends at 320*4*64*16 = 1310720

typedef __attribute__((ext_vector_type(8))) short s16x8;   // 8 bf16 (MFMA A/B frag)
typedef __attribute__((ext_vector_type(4))) float f32x4;   // MFMA C/D frag
typedef __attribute__((ext_vector_type(4))) uint32_t u32x4;

// round-to-nearest f32 -> bf16, packed pair into one u32
__device__ __forceinline__ uint32_t pack_bf16(float a, float b) {
    uint32_t ua = __builtin_bit_cast(uint32_t, a);
    uint32_t ub = __builtin_bit_cast(uint32_t, b);
    ua += 0x7FFFu + ((ua >> 16) & 1u);
    ub += 0x7FFFu + ((ub >> 16) & 1u);
    return (ua >> 16) | (ub & 0xFFFF0000u);
}

__device__ __forceinline__ s16x8 pack_frag(f32x4 lo, f32x4 hi) {
    u32x4 p;
    p.x = pack_bf16(lo.x, lo.y);
    p.y = pack_bf16(lo.z, lo.w);
    p.z = pack_bf16(hi.x, hi.y);
    p.w = pack_bf16(hi.z, hi.w);
    return __builtin_bit_cast(s16x8, p);
}

// Pack x into per-lane-contiguous MFMA B fragments (bf16), zero-padded past K=10000.
// Fragment id = t*4 + c, t in [0,320). Lane L holds B[k=t*32+(L>>4)*8+j][col=c*16+(L&15)].
// Also zeroes the per-row dot accumulator (ws is re-poisoned 0xAA every call).
__global__ __launch_bounds__(256) void pack_x_kernel(const float* __restrict__ x,
                                                     uint32_t* __restrict__ ws,
                                                     float* __restrict__ sacc) {
    int id = blockIdx.x * 256 + threadIdx.x;  // 0 .. 81919
    if (id < N_ROWS) sacc[id] = 0.0f;
    int frag = id >> 6;
    int L = id & 63;
    int t = frag >> 2;
    int c = frag & 3;
    int k0 = t * KTILE + (L >> 4) * 8;
    int col = c * 16 + (L & 15);
    float v[8];
#pragma unroll
    for (int j = 0; j < 8; ++j) {
        int k = k0 + j;
        v[j] = (k < N_ROWS) ? x[k * DIM + col] : 0.0f;
    }
    u32x4 p;
    p.x = pack_bf16(v[0], v[1]);
    p.y = pack_bf16(v[2], v[3]);
    p.z = pack_bf16(v[4], v[5]);
    p.w = pack_bf16(v[6], v[7]);
    ((u32x4*)ws)[id] = p;
}

// blockIdx.x = row tile (16 rows), blockIdx.y*4 + wave = K segment (8 x 40 tiles).
// Per tile: 2 global_load_dwordx4 of A straight to regs (lane (m,quad) reads
// A[rbase+m][t*32+quad*8 ..+8] — exact MFMA A-frag layout, 16x128B contiguous
// segments per wave-instr), in-reg bf16 pack, 4 MFMA against L2-resident B
// frags. 4-deep A prefetch / 2-deep B prefetch, zero __syncthreads.
// Epilogue: per-wave x-dot + 16-lane shuffle reduce + atomicAdd (8 partials/row).
__global__ __launch_bounds__(256, 4) void gemm_dot_kernel(
    const float* __restrict__ A, const float* __restrict__ x,
    const uint32_t* __restrict__ ws, float* __restrict__ sacc) {
    int tid = threadIdx.x;
    int w = tid >> 6;       // wave 0..3
    int L = tid & 63;       // lane
    int quad = L >> 4;      // 0..3
    int m = L & 15;         // A-row-in-tile / B col-in-16
    int rbase = blockIdx.x * 16;
    int t0 = (blockIdx.y * 4 + w) * TPW;

    const float* Ar = A + (size_t)(rbase + m) * N_ROWS;  // this lane's A row
    const u32x4* pb = (const u32x4*)ws;

    // A-frag load for tile t: 8 consecutive floats at k = t*32 + quad*8.
    // Clamp keeps the read in-bounds in the padded region (t >= 312); the
    // matching B fragments are zero there, so the garbage contributes 0.
    auto aload = [&](int t, f32x4& lo, f32x4& hi) {
        int k = t * KTILE + quad * 8;
        if (k > N_ROWS - 8) k = N_ROWS - 8;
        lo = __builtin_nontemporal_load((const f32x4*)(Ar + k));
        hi = __builtin_nontemporal_load((const f32x4*)(Ar + k + 4));
    };
    auto bload = [&](int t, int cc) -> u32x4 {
        return pb[(size_t)t * 256 + cc * 64 + L];
    };

    f32x4 acc[4] = {{0.f, 0.f, 0.f, 0.f},
                    {0.f, 0.f, 0.f, 0.f},
                    {0.f, 0.f, 0.f, 0.f},
                    {0.f, 0.f, 0.f, 0.f}};

    f32x4 alo[PF], ahi[PF];
    u32x4 bb[2][4];

    // ---- prologue: 4 A tiles + 2 B tiles in flight ----
#pragma unroll
    for (int u = 0; u < PF; ++u) aload(t0 + u, alo[u], ahi[u]);
#pragma unroll
    for (int cc = 0; cc < 4; ++cc) bb[0][cc] = bload(t0, cc);
#pragma unroll
    for (int cc = 0; cc < 4; ++cc) bb[1][cc] = bload(t0 + 1, cc);

    for (int tb = 0; tb < TPW; tb += PF) {
#pragma unroll
        for (int u = 0; u < PF; ++u) {      // all buffer indices compile-time
            int i = tb + u;                  // 0..TPW-1
            int t = t0 + i;
            s16x8 af = pack_frag(alo[u], ahi[u]);
#pragma unroll
            for (int cc = 0; cc < 4; ++cc)
                acc[cc] = __builtin_amdgcn_mfma_f32_16x16x32_bf16(
                    af, __builtin_bit_cast(s16x8, bb[u & 1][cc]), acc[cc], 0, 0, 0);
            if (i + 2 < TPW) {               // wave-uniform guard
#pragma unroll
                for (int cc = 0; cc < 4; ++cc) bb[u & 1][cc] = bload(t + 2, cc);
            }
            if (i + PF < TPW)                // wave-uniform guard
                aload(t + PF, alo[u], ahi[u]);
        }
    }

    // Per-wave epilogue. C/D layout: acc[cc][r] = Ax_partial[row=quad*4+r][col=cc*16+m].
    float pr[4];
#pragma unroll
    for (int r = 0; r < 4; ++r) {
        int grow = rbase + quad * 4 + r;
        const float* xr = x + (size_t)grow * DIM + m;
        pr[r] = acc[0][r] * xr[0] + acc[1][r] * xr[16] +
                acc[2][r] * xr[32] + acc[3][r] * xr[48];
        pr[r] += __shfl_xor(pr[r], 1);
        pr[r] += __shfl_xor(pr[r], 2);
        pr[r] += __shfl_xor(pr[r], 4);
        pr[r] += __shfl_xor(pr[r], 8);
    }
    if (m == 0) {
#pragma unroll
        for (int r = 0; r < 4; ++r)
            atomicAdd(&sacc[rbase + quad * 4 + r], pr[r]);
    }
}

__global__ __launch_bounds__(256) void finalize_kernel(const float* __restrict__ x,
                                                       const float* __restrict__ sacc,
                                                       float* __restrict__ out) {
    int id = blockIdx.x * 256 + threadIdx.x;  // 0 .. 159999 (f32x4 units)
    f32x4 xv = ((const f32x4*)x)[id];
    float s = R_CONST * sacc[id >> 4];
    f32x4 o;
    o.x = F_CONST - B_CONST * xv.x - s;
    o.y = F_CONST - B_CONST * xv.y - s;
    o.z = F_CONST - B_CONST * xv.z - s;
    o.w = F_CONST - B_CONST * xv.w - s;
    ((f32x4*)out)[id] = o;
}

extern "C" void kernel_launch(void* const* d_in, const int* in_sizes, int n_in,
                              void* d_out, int out_size, void* d_ws, size_t ws_size,
                              hipStream_t stream) {
    // inputs: t (1, unused), x (10000*64 f32), A (10000*10000 f32)
    const float* x = (const float*)d_in[1];
    const float* A = (const float*)d_in[2];
    float* out = (float*)d_out;
    uint32_t* ws = (uint32_t*)d_ws;  // [0, 1.31MB): packed bf16 x fragments (320 tiles)
    float* sacc = (float*)((char*)d_ws + SACC_OFF_BYTES);  // 40KB row-dot acc

    pack_x_kernel<<<320, 256, 0, stream>>>(x, ws, sacc);
    gemm_dot_kernel<<<dim3(625, KSPLIT), 256, 0, stream>>>(A, x, ws, sacc);
    finalize_kernel<<<625, 256, 0, stream>>>(x, sacc, out);
}

// Round 2
// 541.349 us; speedup vs baseline: 1.0849x; 1.0849x over previous
//
#include <hip/hip_runtime.h>
#include <stdint.h>

// dx/dt = F - B*x - r * rowsum(x * (A@x))  broadcast over DIM
// A: 10000x10000 f32 streamed once (400MB -> ~63.5us HBM floor).
// A@x via bf16 MFMA 16x16x32 (absmax 4.0 vs threshold 20.64 — verified R1).
//
// R6: R4's coalesced 1KB bursts + counted-vmcnt async pipeline.
// Evidence: R5 (reg-direct, 128B/row-stream granules) REGRESSED +63us vs
// R4's staged 1KB bursts -> burst granularity matters, keep staging.
// R4's limiter: load->VGPR->pack->ds_write forces vmcnt(0) self-drain +
// __syncthreads full drain per 16KB chunk (depth-0 pipeline, ~900cy dead
// per chunk). Fix: stage A as f32 via global_load_lds dwordx4 (1KB/instr,
// no VGPR round trip), double-buffered, raw s_barrier + s_waitcnt vmcnt(4)
// so next chunk's stages stay in flight across barriers (T3/T4). B-frag
// loads issued BEFORE stages so their compiler-inserted wait (in-order
// vmcnt) doesn't drain the prefetch. bf16 pack moved to read side. LDS
// XOR-swizzle via pre-swizzled global source (within-1KB 16B-unit perm).
// Predict gemm -> 65-85us, total -> ~355-385us, absmax 4.0.

#define N_ROWS 10000
#define DIM 64
#define KTILE 32
#define NKT 320      // K padded to 10240: 320 tiles of 32; B zero-filled past 10000
#define CHUNK_K 256  // f32 per row per chunk (1KB/row burst)
#define NCHUNK 20    // per K-half: 20*256 = 5120 cols (32-aligned split)
#define KHALF 5120
#define F_CONST 1.0f
#define B_CONST 0.1f
#define R_CONST 0.01f

#define SACC_OFF_BYTES 1310720  // packed B ends at 320*4*64*16 = 1310720

typedef __attribute__((ext_vector_type(8))) short s16x8;   // 8 bf16 (MFMA A/B frag)
typedef __attribute__((ext_vector_type(4))) float f32x4;   // MFMA C/D frag
typedef __attribute__((ext_vector_type(4))) uint32_t u32x4;

// round-to-nearest f32 -> bf16, packed pair into one u32
__device__ __forceinline__ uint32_t pack_bf16(float a, float b) {
    uint32_t ua = __builtin_bit_cast(uint32_t, a);
    uint32_t ub = __builtin_bit_cast(uint32_t, b);
    ua += 0x7FFFu + ((ua >> 16) & 1u);
    ub += 0x7FFFu + ((ub >> 16) & 1u);
    return (ua >> 16) | (ub & 0xFFFF0000u);
}

__device__ __forceinline__ s16x8 pack_frag(f32x4 lo, f32x4 hi) {
    u32x4 p;
    p.x = pack_bf16(lo.x, lo.y);
    p.y = pack_bf16(lo.z, lo.w);
    p.z = pack_bf16(hi.x, hi.y);
    p.w = pack_bf16(hi.z, hi.w);
    return __builtin_bit_cast(s16x8, p);
}

// Pack x into per-lane-contiguous MFMA B fragments (bf16), zero-padded past K=10000.
// Fragment id = t*4 + c, t in [0,320). Lane L holds B[k=t*32+(L>>4)*8+j][col=c*16+(L&15)].
// Also zeroes the per-row dot accumulator (ws is re-poisoned 0xAA every call).
__global__ __launch_bounds__(256) void pack_x_kernel(const float* __restrict__ x,
                                                     uint32_t* __restrict__ ws,
                                                     float* __restrict__ sacc) {
    int id = blockIdx.x * 256 + threadIdx.x;  // 0 .. 81919
    if (id < N_ROWS) sacc[id] = 0.0f;
    int frag = id >> 6;
    int L = id & 63;
    int t = frag >> 2;
    int c = frag & 3;
    int k0 = t * KTILE + (L >> 4) * 8;
    int col = c * 16 + (L & 15);
    float v[8];
#pragma unroll
    for (int j = 0; j < 8; ++j) {
        int k = k0 + j;
        v[j] = (k < N_ROWS) ? x[k * DIM + col] : 0.0f;
    }
    u32x4 p;
    p.x = pack_bf16(v[0], v[1]);
    p.y = pack_bf16(v[2], v[3]);
    p.z = pack_bf16(v[4], v[5]);
    p.w = pack_bf16(v[6], v[7]);
    ((u32x4*)ws)[id] = p;
}

// blockIdx.x = row tile (16 rows), blockIdx.y = K half (20 chunks of 256 each).
// Per chunk: issue 8 B-frag loads (L2/L3-resident ws), then 4 global_load_lds
// dwordx4 staging next chunk (1KB contiguous per instr, f32, source pre-swizzled
// at 16B-unit granularity within each 1KB row-segment), s_waitcnt vmcnt(4)
// (current chunk landed; next chunk's 4 stages stay in flight), raw s_barrier,
// then 2 tiles/wave: swizzled ds_read_b128 x2 -> pack -> 4 MFMA. One more raw
// s_barrier guards the buffer swap. No vmcnt(0) anywhere in the loop.
__global__ __launch_bounds__(256, 4) void gemm_dot_kernel(
    const float* __restrict__ A, const float* __restrict__ x,
    const uint32_t* __restrict__ ws, float* __restrict__ sacc) {
    // f32 tile [16 rows][256 k] per buffer, row stride 1KB = 64 16B-units.
    // Swizzle: global 16B-unit g of row r lands at LDS unit g ^ (r&7)
    // (achieved by pre-swizzling the per-lane global source address; LDS
    // write side of global_load_lds is linear lane*16). Read side applies
    // the same XOR -> 2-way bank aliasing only (free).
    __shared__ __align__(16) float lds[2][16 * CHUNK_K];  // 2 x 16KB

    int tid = threadIdx.x;
    int w = tid >> 6;       // wave 0..3
    int L = tid & 63;       // lane
    int quad = L >> 4;      // 0..3
    int m = L & 15;         // A-row-in-tile / B col-in-16
    int rbase = blockIdx.x * 16;
    int half = blockIdx.y;  // 0,1 -> k in [half*5120, half*5120+5120)
    const float* Ab = A + (size_t)rbase * N_ROWS;
    const u32x4* pb = (const u32x4*)ws;

    // Stage chunk c into buffer b: wave w loads rows w*4..w*4+3, one 1KB
    // row-segment per instruction. Per-lane global col = chunkbase +
    // (L ^ (row&7))*4; clamp keeps the tail read in-bounds (dup data there
    // is multiplied by zero B-frags past k=10000).
    auto stage = [&](int c, int b) {
#pragma unroll
        for (int i = 0; i < 4; ++i) {
            int row = w * 4 + i;
            int col = half * KHALF + c * CHUNK_K + ((L ^ (row & 7)) << 2);
            if (col > N_ROWS - 4) col = N_ROWS - 4;
            __builtin_amdgcn_global_load_lds(
                (const __attribute__((address_space(1))) uint32_t*)(Ab + (size_t)row * N_ROWS + col),
                (__attribute__((address_space(3))) uint32_t*)(&lds[b][row * CHUNK_K]),
                16, 0, 0);
        }
    };

    f32x4 acc[4] = {{0.f, 0.f, 0.f, 0.f},
                    {0.f, 0.f, 0.f, 0.f},
                    {0.f, 0.f, 0.f, 0.f},
                    {0.f, 0.f, 0.f, 0.f}};
    u32x4 bb[8];

    stage(0, 0);
    int b = 0;
    for (int c = 0; c < NCHUNK; ++c) {
        // B-frags for this chunk's 2 tiles FIRST (so the compiler's wait for
        // them doesn't drain the stage prefetch behind them).
        int T0 = half * (NKT / 2) + c * 8;
#pragma unroll
        for (int cc = 0; cc < 4; ++cc) bb[cc] = pb[(size_t)(T0 + w) * 256 + cc * 64 + L];
#pragma unroll
        for (int cc = 0; cc < 4; ++cc) bb[4 + cc] = pb[(size_t)(T0 + w + 4) * 256 + cc * 64 + L];
        __builtin_amdgcn_sched_barrier(0);  // pin bloads above the stages
        if (c + 1 < NCHUNK) stage(c + 1, b ^ 1);
        // Outstanding here: stage(c) [4] + bload(c) [8] + stage(c+1) [4].
        // vmcnt(4): chunk c landed in LDS, bloads landed, stage(c+1) in flight.
        asm volatile("s_waitcnt vmcnt(4)" ::: "memory");
        __builtin_amdgcn_s_barrier();

        // MFMA on buffer b: wave w handles tiles w and w+4 of this chunk
#pragma unroll
        for (int u = 0; u < 2; ++u) {
            int tt = w + 4 * u;
            int u0 = tt * 8 + quad * 2;  // 16B-unit of k = tt*32 + quad*8
            const char* base = (const char*)&lds[b][0] + m * (CHUNK_K * 4);
            f32x4 lo = *(const f32x4*)(base + (((u0) ^ (m & 7)) << 4));
            f32x4 hi = *(const f32x4*)(base + (((u0 + 1) ^ (m & 7)) << 4));
            s16x8 af = pack_frag(lo, hi);
#pragma unroll
            for (int cc = 0; cc < 4; ++cc)
                acc[cc] = __builtin_amdgcn_mfma_f32_16x16x32_bf16(
                    af, __builtin_bit_cast(s16x8, bb[u * 4 + cc]), acc[cc], 0, 0, 0);
        }
        __builtin_amdgcn_s_barrier();  // all reads of buf b done before it's re-staged
        b ^= 1;
    }

    // Per-wave epilogue. C/D layout: acc[cc][r] = Ax_partial[row=quad*4+r][col=cc*16+m].
    float pr[4];
#pragma unroll
    for (int r = 0; r < 4; ++r) {
        int grow = rbase + quad * 4 + r;
        const float* xr = x + (size_t)grow * DIM + m;
        pr[r] = acc[0][r] * xr[0] + acc[1][r] * xr[16] +
                acc[2][r] * xr[32] + acc[3][r] * xr[48];
        pr[r] += __shfl_xor(pr[r], 1);
        pr[r] += __shfl_xor(pr[r], 2);
        pr[r] += __shfl_xor(pr[r], 4);
        pr[r] += __shfl_xor(pr[r], 8);
    }
    if (m == 0) {
#pragma unroll
        for (int r = 0; r < 4; ++r)
            atomicAdd(&sacc[rbase + quad * 4 + r], pr[r]);
    }
}

__global__ __launch_bounds__(256) void finalize_kernel(const float* __restrict__ x,
                                                       const float* __restrict__ sacc,
                                                       float* __restrict__ out) {
    int id = blockIdx.x * 256 + threadIdx.x;  // 0 .. 159999 (f32x4 units)
    f32x4 xv = ((const f32x4*)x)[id];
    float s = R_CONST * sacc[id >> 4];
    f32x4 o;
    o.x = F_CONST - B_CONST * xv.x - s;
    o.y = F_CONST - B_CONST * xv.y - s;
    o.z = F_CONST - B_CONST * xv.z - s;
    o.w = F_CONST - B_CONST * xv.w - s;
    ((f32x4*)out)[id] = o;
}

extern "C" void kernel_launch(void* const* d_in, const int* in_sizes, int n_in,
                              void* d_out, int out_size, void* d_ws, size_t ws_size,
                              hipStream_t stream) {
    // inputs: t (1, unused), x (10000*64 f32), A (10000*10000 f32)
    const float* x = (const float*)d_in[1];
    const float* A = (const float*)d_in[2];
    float* out = (float*)d_out;
    uint32_t* ws = (uint32_t*)d_ws;  // [0, 1.31MB): packed bf16 x fragments (320 tiles)
    float* sacc = (float*)((char*)d_ws + SACC_OFF_BYTES);  // 40KB row-dot acc

    pack_x_kernel<<<320, 256, 0, stream>>>(x, ws, sacc);
    gemm_dot_kernel<<<dim3(625, 2), 256, 0, stream>>>(A, x, ws, sacc);
    finalize_kernel<<<625, 256, 0, stream>>>(x, sacc, out);
}